// Round 1
// baseline (302.651 us; speedup 1.0000x reference)
//
#include <hip/hip_runtime.h>
#include <hip/hip_bf16.h>
#include <stdint.h>

// Problem constants (from reference): B=8, S=2048, D_IN=4096, D_OUT=4096
#define MROWS 16384   // B*S
#define DIN   4096
#define DOUT  4096
#define KEFF  1024    // DIN * 2/8 (mask keeps d%8 in {0,2})

typedef __attribute__((ext_vector_type(8))) __bf16 bf16x8;
typedef __attribute__((ext_vector_type(4))) float f32x4;

__device__ __forceinline__ uint32_t f2bf_rne(float f) {
  union { float f; uint32_t u; } v; v.f = f;
  uint32_t u = v.u;
  return (u + 0x7fffu + ((u >> 16) & 1u)) >> 16;
}

// Gather 2-of-8 pattern (positions 0 and 2 of each group of 8), convert to
// bf16, pack pairs into u32.  dst[i] packs group i: (bf16(src[8i]), bf16(src[8i+2])).
__global__ void venom_gather(const float* __restrict__ src,
                             uint32_t* __restrict__ dst, int ngroups) {
  int stride = gridDim.x * blockDim.x;
  for (int i = blockIdx.x * blockDim.x + threadIdx.x; i < ngroups; i += stride) {
    const float4 v = *reinterpret_cast<const float4*>(src + (size_t)i * 8);
    uint32_t lo = f2bf_rne(v.x);
    uint32_t hi = f2bf_rne(v.z);
    dst[i] = lo | (hi << 16);
  }
}

// ---------------- bf16 GEMM, m97 structure: 128x128 tile, BK=32 ----------------
// A = Xg [MROWS][KEFF] row-major bf16, B = Wg [DOUT][KEFF] row-major bf16 (B^T form).
// C[m][n] = sum_k A[m][k]*B[n][k] + bias[n], C fp32 row-major.
#define BM 128
#define BN 128
#define BK 32

__global__ __launch_bounds__(256) void venom_gemm(
    const __bf16* __restrict__ A, const __bf16* __restrict__ Bm,
    const float* __restrict__ bias, float* __restrict__ C) {
  __shared__ __bf16 As[BM * BK];  // 8 KB
  __shared__ __bf16 Bs[BN * BK];  // 8 KB

  const int nblkN = DOUT / BN;  // 32
  // XCD-aware swizzle; grid = 4096 (divisible by 8) -> bijective
  int nwg = gridDim.x;
  int cpx = nwg >> 3;
  int bid = blockIdx.x;
  int swz = (bid & 7) * cpx + (bid >> 3);
  int mblk = swz / nblkN;
  int nblk = swz % nblkN;

  int t = threadIdx.x;
  int w = t >> 6;          // wave id 0..3
  int l = t & 63;          // lane
  int wr = w >> 1, wc = w & 1;
  int lr = l & 15;         // row/col within 16x16 frag
  int lk = (l >> 4) * 8;   // k offset within frag

  const __bf16* Ag = A + (size_t)mblk * BM * KEFF;
  const __bf16* Bg = Bm + (size_t)nblk * BN * KEFF;

  f32x4 acc[4][4] = {};

  for (int k0 = 0; k0 < KEFF; k0 += BK) {
    // Stage A and B tiles: 128x32 bf16 = 8 KB each; 256 thr x 16 B = 4 KB/issue.
    #pragma unroll
    for (int i = 0; i < 2; ++i) {
      int e = i * 256 + t;       // octet index (8 bf16 per thread)
      int r = e >> 2;            // row 0..127
      int c = (e & 3) * 8;       // k column 0,8,16,24
      __builtin_amdgcn_global_load_lds(
          (const __attribute__((address_space(1))) uint32_t*)(Ag + (size_t)r * KEFF + k0 + c),
          (__attribute__((address_space(3))) uint32_t*)(&As[e * 8]), 16, 0, 0);
      __builtin_amdgcn_global_load_lds(
          (const __attribute__((address_space(1))) uint32_t*)(Bg + (size_t)r * KEFF + k0 + c),
          (__attribute__((address_space(3))) uint32_t*)(&Bs[e * 8]), 16, 0, 0);
    }
    __syncthreads();

    bf16x8 af[4], bfr[4];
    #pragma unroll
    for (int mi = 0; mi < 4; ++mi)
      af[mi] = *reinterpret_cast<const bf16x8*>(&As[(wr * 64 + mi * 16 + lr) * BK + lk]);
    #pragma unroll
    for (int ni = 0; ni < 4; ++ni)
      bfr[ni] = *reinterpret_cast<const bf16x8*>(&Bs[(wc * 64 + ni * 16 + lr) * BK + lk]);

    #pragma unroll
    for (int mi = 0; mi < 4; ++mi)
      #pragma unroll
      for (int ni = 0; ni < 4; ++ni)
        acc[mi][ni] = __builtin_amdgcn_mfma_f32_16x16x32_bf16(af[mi], bfr[ni],
                                                              acc[mi][ni], 0, 0, 0);
    __syncthreads();
  }

  // Epilogue: C/D layout col = lane&15, row = (lane>>4)*4 + j  [m89/m91 verified]
  int colbase = nblk * BN + wc * 64;
  int rowbase = mblk * BM + wr * 64;
  #pragma unroll
  for (int ni = 0; ni < 4; ++ni) {
    int col = colbase + ni * 16 + lr;
    float bv = bias[col];
    #pragma unroll
    for (int mi = 0; mi < 4; ++mi) {
      int row0 = rowbase + mi * 16 + (l >> 4) * 4;
      f32x4 cv = acc[mi][ni];
      #pragma unroll
      for (int j = 0; j < 4; ++j)
        C[(size_t)(row0 + j) * DOUT + col] = cv[j] + bv;
    }
  }
}

// Correct-but-slow fallback if workspace is too small (should not trigger).
__global__ void venom_naive(const float* __restrict__ x, const float* __restrict__ w,
                            const float* __restrict__ bias, float* __restrict__ out) {
  size_t total = (size_t)MROWS * DOUT;
  size_t stride = (size_t)gridDim.x * blockDim.x;
  for (size_t idx = (size_t)blockIdx.x * blockDim.x + threadIdx.x; idx < total;
       idx += stride) {
    int m = (int)(idx / DOUT), n = (int)(idx % DOUT);
    const float* xr = x + (size_t)m * DIN;
    const float* wr = w + (size_t)n * DIN;
    float s = 0.f;
    for (int g = 0; g < DIN / 8; ++g)
      s += xr[g * 8] * wr[g * 8] + xr[g * 8 + 2] * wr[g * 8 + 2];
    out[idx] = s + bias[n];
  }
}

extern "C" void kernel_launch(void* const* d_in, const int* in_sizes, int n_in,
                              void* d_out, int out_size, void* d_ws, size_t ws_size,
                              hipStream_t stream) {
  const float* x    = (const float*)d_in[0];
  const float* wgt  = (const float*)d_in[1];
  const float* bias = (const float*)d_in[2];
  float* out = (float*)d_out;

  const size_t xg_bytes = (size_t)MROWS * KEFF * 2;  // 33.5 MB
  const size_t wg_bytes = (size_t)DOUT * KEFF * 2;   //  8.4 MB

  if (ws_size < xg_bytes + wg_bytes) {
    venom_naive<<<2048, 256, 0, stream>>>(x, wgt, bias, out);
    return;
  }

  uint32_t* xg = (uint32_t*)d_ws;
  uint32_t* wg = (uint32_t*)((char*)d_ws + xg_bytes);

  venom_gather<<<2048, 256, 0, stream>>>(x, xg, MROWS * (DIN / 8));
  venom_gather<<<512, 256, 0, stream>>>(wgt, wg, DOUT * (DIN / 8));

  venom_gemm<<<(MROWS / BM) * (DOUT / BN), 256, 0, stream>>>(
      (const __bf16*)xg, (const __bf16*)wg, bias, out);
}

// Round 2
// 289.763 us; speedup vs baseline: 1.0445x; 1.0445x over previous
//
#include <hip/hip_runtime.h>
#include <hip/hip_bf16.h>
#include <stdint.h>

// Problem constants: B=8, S=2048, D_IN=4096, D_OUT=4096
#define MROWS 16384   // B*S
#define DIN   4096
#define DOUT  4096
#define KEFF  1024    // DIN * 2/8 (mask keeps d%8 in {0,2})

typedef __attribute__((ext_vector_type(8))) __bf16 bf16x8;
typedef __attribute__((ext_vector_type(4))) float f32x4;

__device__ __forceinline__ uint32_t f2bf_rne(float f) {
  union { float f; uint32_t u; } v; v.f = f;
  uint32_t u = v.u;
  return (u + 0x7fffu + ((u >> 16) & 1u)) >> 16;
}

// Gather 2-of-8 (positions 0,2 of each group of 8), fp32 -> bf16, pack pairs.
__global__ void venom_gather(const float* __restrict__ src,
                             uint32_t* __restrict__ dst, int ngroups) {
  int stride = gridDim.x * blockDim.x;
  for (int i = blockIdx.x * blockDim.x + threadIdx.x; i < ngroups; i += stride) {
    const float4 v = *reinterpret_cast<const float4*>(src + (size_t)i * 8);
    dst[i] = f2bf_rne(v.x) | (f2bf_rne(v.z) << 16);
  }
}

// ---------------- 256x256 8-phase bf16 GEMM (T1+T2+T3/T4+T5) ----------------
// A = Xg [MROWS][KEFF] bf16 row-major, B = Wg [DOUT][KEFF] bf16 row-major (B^T).
// C[m][n] = sum_k A[m][k]*B[n][k] + bias[n], fp32 row-major.
#define BM 256
#define BN 256
#define BK 64
#define NT (KEFF / BK)   // 16

__global__ __launch_bounds__(512, 2) void venom_gemm(
    const __bf16* __restrict__ A, const __bf16* __restrict__ Bm,
    const float* __restrict__ bias, float* __restrict__ C) {
  // 2 x (32KB A + 32KB B) = 128 KiB
  __shared__ __bf16 As[2][BM * BK];
  __shared__ __bf16 Bs[2][BN * BK];

  const int nblkN = DOUT / BN;  // 16
  // XCD-aware bijective swizzle (grid=1024, %8==0)
  int nwg = gridDim.x;
  int cpx = nwg >> 3;
  int bid = blockIdx.x;
  int swz = (bid & 7) * cpx + (bid >> 3);
  int mblk = swz / nblkN;
  int nblk = swz % nblkN;

  int t = threadIdx.x;
  int wid = t >> 6, l = t & 63;
  int wr = wid >> 2, wc = wid & 3;   // 2x4 wave grid; wave owns 128x64 of C
  int lr = l & 15, lg = l >> 4;      // frag row/col, k-group
  int lswz = (l & 7) << 4;           // XOR swizzle bits (row&7 == lr&7 == l&7)

  const __bf16* Ag = A + (size_t)(mblk * BM) * KEFF;
  const __bf16* Bg = Bm + (size_t)(nblk * BN) * KEFF;

  f32x4 acc[8][4] = {};

  // Stage one K-tile (A 32KB + B 32KB) into buf. Linear LDS dest (wave-uniform
  // base + lane*16), inverse-swizzled GLOBAL source (rule #21).
  auto stage = [&](int buf, int kt) {
    const int k0 = kt * BK;
    #pragma unroll
    for (int i = 0; i < 4; ++i) {
      int e = i * 512 + t;               // 16B chunk index, 0..2047
      int row = e >> 3;                  // 8 chunks per 128B row
      int inL = ((e & 7) * 16) ^ ((row & 7) << 4);  // logical byte within row
      __builtin_amdgcn_global_load_lds(
          (const __attribute__((address_space(1))) uint32_t*)(Ag + (size_t)row * KEFF + k0 + (inL >> 1)),
          ((__attribute__((address_space(3))) uint32_t*)&As[buf][0]) + e * 4, 16, 0, 0);
    }
    #pragma unroll
    for (int i = 0; i < 4; ++i) {
      int e = i * 512 + t;
      int row = e >> 3;
      int inL = ((e & 7) * 16) ^ ((row & 7) << 4);
      __builtin_amdgcn_global_load_lds(
          (const __attribute__((address_space(1))) uint32_t*)(Bg + (size_t)row * KEFF + k0 + (inL >> 1)),
          ((__attribute__((address_space(3))) uint32_t*)&Bs[buf][0]) + e * 4, 16, 0, 0);
    }
  };

  // Prologue: tile 0
  stage(0, 0);
  asm volatile("s_waitcnt vmcnt(0)" ::: "memory");
  __builtin_amdgcn_s_barrier();

  bf16x8 bfrag[4];

  for (int kt = 0; kt < NT; ++kt) {
    int cur = kt & 1, nxt = cur ^ 1, t1 = kt + 1;
    const char* asBase = (const char*)&As[cur][0];
    const char* bsBase = (const char*)&Bs[cur][0];

    // 4 phases: (mh,kh) = (0,0),(1,0),(0,1),(1,1); 16 MFMA each.
    #pragma unroll
    for (int ph = 0; ph < 4; ++ph) {
      const int mh = ph & 1, kh = ph >> 1;
      const int kswz = (kh * 64 + lg * 16) ^ lswz;

      bf16x8 af[4];
      #pragma unroll
      for (int mi = 0; mi < 4; ++mi)
        af[mi] = *(const bf16x8*)(asBase +
                   (wr * 128 + mh * 64 + mi * 16 + lr) * 128 + kswz);
      if (mh == 0) {
        #pragma unroll
        for (int ni = 0; ni < 4; ++ni)
          bfrag[ni] = *(const bf16x8*)(bsBase +
                       (wc * 64 + ni * 16 + lr) * 128 + kswz);
      }
      if (ph == 0 && t1 < NT) stage(nxt, t1);  // front-load next-tile prefetch

      __builtin_amdgcn_s_barrier();
      __builtin_amdgcn_s_setprio(1);
      #pragma unroll
      for (int mi = 0; mi < 4; ++mi)
        #pragma unroll
        for (int ni = 0; ni < 4; ++ni)
          acc[mh * 4 + mi][ni] = __builtin_amdgcn_mfma_f32_16x16x32_bf16(
              af[mi], bfrag[ni], acc[mh * 4 + mi][ni], 0, 0, 0);
      __builtin_amdgcn_s_setprio(0);
      if (ph < 3) __builtin_amdgcn_s_barrier();
    }

    // Tile boundary: my next-tile stage loads must be done; all waves' reads
    // of buf cur are complete (lgkm waits before their MFMAs).
    if (t1 < NT) asm volatile("s_waitcnt vmcnt(0)" ::: "memory");
    __builtin_amdgcn_s_barrier();
  }

  // Epilogue: C/D layout col=lane&15, row=(lane>>4)*4+j  [m89/m91]
  int colbase = nblk * BN + wc * 64;
  int rowbase = mblk * BM + wr * 128;
  #pragma unroll
  for (int mh = 0; mh < 2; ++mh)
    #pragma unroll
    for (int mi = 0; mi < 4; ++mi) {
      int row0 = rowbase + mh * 64 + mi * 16 + lg * 4;
      #pragma unroll
      for (int ni = 0; ni < 4; ++ni) {
        int col = colbase + ni * 16 + lr;
        float bv = bias[col];
        f32x4 cv = acc[mh * 4 + mi][ni];
        #pragma unroll
        for (int j = 0; j < 4; ++j)
          C[(size_t)(row0 + j) * DOUT + col] = cv[j] + bv;
      }
    }
}

// Correct-but-slow fallback if workspace is too small (should not trigger).
__global__ void venom_naive(const float* __restrict__ x, const float* __restrict__ w,
                            const float* __restrict__ bias, float* __restrict__ out) {
  size_t total = (size_t)MROWS * DOUT;
  size_t stride = (size_t)gridDim.x * blockDim.x;
  for (size_t idx = (size_t)blockIdx.x * blockDim.x + threadIdx.x; idx < total;
       idx += stride) {
    int m = (int)(idx / DOUT), n = (int)(idx % DOUT);
    const float* xr = x + (size_t)m * DIN;
    const float* wr = w + (size_t)n * DIN;
    float s = 0.f;
    for (int g = 0; g < DIN / 8; ++g)
      s += xr[g * 8] * wr[g * 8] + xr[g * 8 + 2] * wr[g * 8 + 2];
    out[idx] = s + bias[n];
  }
}

extern "C" void kernel_launch(void* const* d_in, const int* in_sizes, int n_in,
                              void* d_out, int out_size, void* d_ws, size_t ws_size,
                              hipStream_t stream) {
  const float* x    = (const float*)d_in[0];
  const float* wgt  = (const float*)d_in[1];
  const float* bias = (const float*)d_in[2];
  float* out = (float*)d_out;

  const size_t xg_bytes = (size_t)MROWS * KEFF * 2;  // 33.5 MB
  const size_t wg_bytes = (size_t)DOUT * KEFF * 2;   //  8.4 MB

  if (ws_size < xg_bytes + wg_bytes) {
    venom_naive<<<2048, 256, 0, stream>>>(x, wgt, bias, out);
    return;
  }

  uint32_t* xg = (uint32_t*)d_ws;
  uint32_t* wg = (uint32_t*)((char*)d_ws + xg_bytes);

  venom_gather<<<2048, 256, 0, stream>>>(x, xg, MROWS * (DIN / 8));
  venom_gather<<<512, 256, 0, stream>>>(wgt, wg, DOUT * (DIN / 8));

  venom_gemm<<<(MROWS / BM) * (DOUT / BN), 512, 0, stream>>>(
      (const __bf16*)xg, (const __bf16*)wg, bias, out);
}